// Round 10
// baseline (414.971 us; speedup 1.0000x reference)
//
#include <hip/hip_runtime.h>
#include <hip/hip_bf16.h>

// Problem constants
#define Bc   2
#define Nc   4096
#define Hc   4
#define HIDc 256
#define VDc  64

typedef short s8v  __attribute__((ext_vector_type(8)));
typedef float f4v  __attribute__((ext_vector_type(4)));

static __device__ __forceinline__ unsigned short bf16bits(float f) {
    __hip_bfloat16 h = __float2bfloat16(f);
    return *(unsigned short*)&h;
}

// ---------------------------------------------------------------------------
// K1 (fused): blocks 0..127 = W-prep (bf16 hi/lo split into MFMA-A-fragment-
// linear layout); blocks 128..8319 = per-row exact 30th percentile + row min.
// Thresh: windowed histogram on [0.25,0.35] (ranks 1228/1229 of U[0,1) rows
// land there with ~7 sigma margin); exact full-range fallback if not.
// ---------------------------------------------------------------------------
__global__ __launch_bounds__(256) void front_kernel(
    const float* __restrict__ m_dist, const float* __restrict__ wgt,
    unsigned short* __restrict__ wh, unsigned short* __restrict__ wl,
    float* __restrict__ thr_out, float* __restrict__ min_out)
{
    int t = threadIdx.x, bid = blockIdx.x;

    if (bid < 128) {
        int h  = bid >> 5;
        int kt = (bid >> 3) & 3;
        int jc = bid & 7;
        int lane = t >> 2, ii = t & 3;
        #pragma unroll
        for (int u = 0; u < 2; u++) {
            int i = ii * 2 + u;
            int j = jc * 32 + (lane >> 4) * 8 + i;
            int k = kt * 16 + (lane & 15);
            float v = wgt[((size_t)h * HIDc + j) * VDc + k];
            __hip_bfloat16 hb = __float2bfloat16(v);
            float hf = __bfloat162float(hb);
            size_t o = ((((size_t)h * 4 + kt) * 8 + jc) * 64 + lane) * 8 + i;
            wh[o] = *(unsigned short*)&hb;
            wl[o] = bf16bits(v - hf);
        }
        return;
    }

    __shared__ unsigned int hist[1024];
    __shared__ float wredf[4];
    __shared__ unsigned int wsum[4];
    __shared__ unsigned int wscan[4];
    __shared__ int b0s, b1s;
    __shared__ unsigned int c0s;
    __shared__ unsigned int ncand;
    __shared__ float cand[256];
    __shared__ float s0s, s1s;

    size_t rowid = bid - 128;
    const float* row = m_dist + rowid * Nc;

    float4 vals[4];
    float lmin = 1e30f;
    #pragma unroll
    for (int i = 0; i < 4; i++) {
        float4 v = ((const float4*)row)[t + i * 256];
        vals[i] = v;
        lmin = fminf(lmin, fminf(fminf(v.x, v.y), fminf(v.z, v.w)));
    }
    #pragma unroll
    for (int o = 32; o > 0; o >>= 1) lmin = fminf(lmin, __shfl_xor(lmin, o));
    if ((t & 63) == 0) wredf[t >> 6] = lmin;

    const unsigned int R0 = 1228u, R1 = 1229u;
    float wlo = 0.25f, whi = 0.35f;
    int b0 = 0, b1 = 0;
    unsigned int C0 = 0;

    for (;;) {
        float wscale = 1024.0f / (whi - wlo);

        for (int i = t; i < 1024; i += 256) hist[i] = 0u;
        if (t == 0) ncand = 0u;
        __syncthreads();

        unsigned int cb = 0;
        #pragma unroll
        for (int i = 0; i < 4; i++) {
            float a[4] = {vals[i].x, vals[i].y, vals[i].z, vals[i].w};
            #pragma unroll
            for (int j = 0; j < 4; j++) {
                float v = a[j];
                if (v < wlo) {
                    cb++;
                } else {
                    int bx = (int)((v - wlo) * wscale);
                    if (bx < 1024) atomicAdd(&hist[bx], 1u);
                }
            }
        }
        #pragma unroll
        for (int o = 32; o > 0; o >>= 1) cb += __shfl_xor(cb, o);
        if ((t & 63) == 0) wsum[t >> 6] = cb;
        __syncthreads();
        unsigned int Cb = wsum[0] + wsum[1] + wsum[2] + wsum[3];

        unsigned int c[4], csum = 0;
        #pragma unroll
        for (int j = 0; j < 4; j++) { c[j] = hist[t * 4 + j]; csum += c[j]; }
        unsigned int inc = csum;
        #pragma unroll
        for (int o = 1; o < 64; o <<= 1) {
            unsigned int nv = __shfl_up(inc, o);
            if ((t & 63) >= o) inc += nv;
        }
        if ((t & 63) == 63) wscan[t >> 6] = inc;
        __syncthreads();
        unsigned int wpref = 0;
        for (int wv = 0; wv < (t >> 6); wv++) wpref += wscan[wv];
        unsigned int T = wscan[0] + wscan[1] + wscan[2] + wscan[3];
        unsigned int P = Cb + wpref + inc - csum;

        unsigned int cum = P;
        #pragma unroll
        for (int j = 0; j < 4; j++) {
            unsigned int lo = cum, hi = cum + c[j];
            if (R0 >= lo && R0 < hi) { b0s = t * 4 + j; c0s = lo; }
            if (R1 >= lo && R1 < hi) { b1s = t * 4 + j; }
            cum = hi;
        }
        __syncthreads();

        if (Cb <= R0 && R1 < Cb + T) { b0 = b0s; b1 = b1s; C0 = c0s; break; }
        wlo = 0.0f; whi = 1.001f;
    }

    float wscale = 1024.0f / (whi - wlo);
    #pragma unroll
    for (int i = 0; i < 4; i++) {
        float a[4] = {vals[i].x, vals[i].y, vals[i].z, vals[i].w};
        #pragma unroll
        for (int j = 0; j < 4; j++) {
            float v = a[j];
            if (v >= wlo) {
                int bx = (int)((v - wlo) * wscale);
                if (bx >= b0 && bx <= b1) {
                    unsigned int p = atomicAdd(&ncand, 1u);
                    if (p < 256u) cand[p] = v;
                }
            }
        }
    }
    __syncthreads();
    unsigned int nc = min(ncand, 256u);
    if ((unsigned int)t < nc) {
        float v = cand[t];
        unsigned int rk = C0;
        for (unsigned int j = 0; j < nc; j++) {
            float u = cand[j];
            rk += (u < v || (u == v && j < (unsigned int)t)) ? 1u : 0u;
        }
        if (rk == R0) s0s = v;
        if (rk == R1) s1s = v;
    }
    __syncthreads();
    if (t == 0) {
        thr_out[rowid] = 0.5f * (s0s + s1s);
        min_out[rowid] = fminf(fminf(wredf[0], wredf[1]), fminf(wredf[2], wredf[3]));
    }
}

// ---------------------------------------------------------------------------
// K2: V^T via MFMA, 3-term bf16 split (Ah*Bh + Al*Bh + Ah*Bl ~ f32-accurate).
// x converted f32 -> bf16 hi/lo inline. VT[b,h,k,n] bf16 directly.
// grid = B*H*(N/64) = 512 blocks x 256 (4 waves; wave w owns n-subtile w).
// ---------------------------------------------------------------------------
__global__ __launch_bounds__(256) void value_kernel(
    const float* __restrict__ x,
    const unsigned short* __restrict__ wh, const unsigned short* __restrict__ wl,
    unsigned short* __restrict__ vt_g)
{
    int t  = threadIdx.x;
    int bid = blockIdx.x;
    int nt = bid & 63;
    int h  = (bid >> 6) & 3;
    int b  = bid >> 8;
    int n0 = nt * 64;

    int w = t >> 6, lane = t & 63, q4 = lane >> 4, m16 = lane & 15;
    int nb = n0 + w * 16;

    const float* xp = x + ((size_t)(b * Nc + nb + m16)) * HIDc + q4 * 8;

    f4v acc[4];
    #pragma unroll
    for (int kt = 0; kt < 4; kt++) acc[kt] = (f4v){0.f, 0.f, 0.f, 0.f};

    #pragma unroll
    for (int jc = 0; jc < 8; jc++) {
        float4 xv0 = *(const float4*)(xp + jc * 32);
        float4 xv1 = *(const float4*)(xp + jc * 32 + 4);
        float f[8] = {xv0.x, xv0.y, xv0.z, xv0.w, xv1.x, xv1.y, xv1.z, xv1.w};
        union { s8v v; unsigned short u[8]; } hs, ls;
        #pragma unroll
        for (int i = 0; i < 8; i++) {
            __hip_bfloat16 hb = __float2bfloat16(f[i]);
            float hf = __bfloat162float(hb);
            hs.u[i] = *(unsigned short*)&hb;
            ls.u[i] = bf16bits(f[i] - hf);
        }
        #pragma unroll
        for (int kt = 0; kt < 4; kt++) {
            size_t ao = (((size_t)(h * 4 + kt) * 8 + jc) << 9) + lane * 8;
            s8v ah = *(const s8v*)(wh + ao);
            s8v al = *(const s8v*)(wl + ao);
            acc[kt] = __builtin_amdgcn_mfma_f32_16x16x32_bf16(ah, hs.v, acc[kt], 0, 0, 0);
            acc[kt] = __builtin_amdgcn_mfma_f32_16x16x32_bf16(al, hs.v, acc[kt], 0, 0, 0);
            acc[kt] = __builtin_amdgcn_mfma_f32_16x16x32_bf16(ah, ls.v, acc[kt], 0, 0, 0);
        }
    }

    unsigned short* vg = vt_g + (((size_t)b * Hc + h) * VDc) * Nc;
    #pragma unroll
    for (int kt = 0; kt < 4; kt++) {
        #pragma unroll
        for (int rg = 0; rg < 4; rg++) {
            int k = kt * 16 + q4 * 4 + rg;
            vg[(size_t)k * Nc + nb + m16] = bf16bits(acc[kt][rg]);
        }
    }
}

// ---------------------------------------------------------------------------
// K3: fused mask + softmax-numerator + PV (bf16 MFMA), split-K over j.
// R10 = R9 skeleton with the TWO measured defects fixed:
//  (1) vt bank conflicts (R9: SQ_LDS_BANK_CONFLICT=4.19M): JT 32->64 restores
//      the R3 layout (128B rows, 8x16B chunks, ^(row&7) source-side swizzle)
//      which MEASURED 0 conflicts on this exact B-read pattern. Each 16-lane
//      read-group now spans all 8 bank-quads (chunk = (ks*4+q)^(m16&7)).
//  (2) exposed A-latency (R8->R9 regression mechanism): the ks0 A-pair is
//      REGISTER-prefetched one iteration ahead (8 VGPRs, not the old 64-VGPR
//      -busting tile); the ks1 pair is issued at compute start and covered by
//      ks0's exp+MFMA. Issue order (ks1, prefetch, DMA) keeps the compiler's
//      dependency-exact vmcnt from draining the prefetch/DMA early.
// Double-buffered vt (2x32KB, 2 blocks/CU via (1024,8)); ONE barrier/iter
// (16 iters); premask inline: w = (d<=thm) ? exp2(fma(d,cc,nmncc)) : 0.
// Numerics: per-element formulas, MFMA j-order, reduction trees identical
// to R8/R9 -> bit-identical output (absmax change = regression canary).
// ---------------------------------------------------------------------------
#define NT 64
#define JT 64

__global__ __launch_bounds__(1024, 8) void attn_kernel(
    const float* __restrict__ m_dist, const float* __restrict__ rr,
    const unsigned short* __restrict__ vt_g,
    const float* __restrict__ thr_g, const float* __restrict__ min_g,
    float* __restrict__ Op, float* __restrict__ Zp, int jlen)
{
    __shared__ unsigned short vt[2][Hc * VDc * JT];   // 2 x 32 KB

    int t = threadIdx.x;
    const int nblk = Bc * (Nc / NT);        // 128
    int js = blockIdx.x / nblk;
    int rb = blockIdx.x - js * nblk;
    int b  = rb >> 6;                       // Nc/NT = 64 row-tiles
    int n0 = (rb & 63) * NT;
    int j0 = js * jlen;

    int lane = t & 63, q = lane >> 4, m16 = lane & 15;
    int w = t >> 6;                         // wave 0..15
    int h = w & 3, rq = w >> 2;             // head, row-quad
    int row = rq * 16 + m16;                // local A-row this lane owns (0..63)

    float mn  = min_g[b * Nc + n0 + row];
    float thm = thr_g[b * Nc + n0 + row];
    float rv = rr[h];
    float cc = -(rv * rv) * 1.4426950408889634f;   // -r^2 * log2(e)
    float nmncc = -mn * cc;                        // w = exp2(fma(d, cc, nmncc))

    f4v acc[4];
    #pragma unroll
    for (int ct = 0; ct < 4; ct++) acc[ct] = (f4v){0.f, 0.f, 0.f, 0.f};
    float zacc = 0.f;

    // per-lane direct A source: m_dist[b][n0+row][j0 + q*8 + ...]
    const float* arow = m_dist + ((size_t)b * Nc + n0 + row) * Nc + j0 + q * 8;

    // vt DMA staging (2 DMAs/thread): row r = (t>>3) + i*128 (128B rows),
    // phys 16B-chunk t&7, logical source chunk (t&7)^(r&7), r&7 == (t>>3)&7.
    // LDS dest linear = i*16KB + t*16 B (wave-uniform base + lane*16).
    const unsigned short* vtb = vt_g + ((size_t)b * Hc * VDc) * Nc + j0;
    const unsigned short* vsrc  = vtb + (size_t)(t >> 3) * Nc + (((t & 7) ^ ((t >> 3) & 7)) << 3);
    const unsigned short* vsrc2 = vsrc + (size_t)128 * Nc;

    // B-read swizzled chunk offsets (ushorts within 64-ushort row)
    int bc0 = ((q ^ (m16 & 7)) << 3);        // ks=0: logical chunk q
    int bc1 = (((4 + q) ^ (m16 & 7)) << 3);  // ks=1: logical chunk 4+q
    const int hoff = h * VDc * JT;

    int niter = jlen / JT;                   // 16

    #define STAGE(k, bi) do {                                                    \
        size_t jo_ = (size_t)(k) * JT;                                           \
        __builtin_amdgcn_global_load_lds(                                        \
            (const __attribute__((address_space(1))) void*)(vsrc + jo_),         \
            (__attribute__((address_space(3))) void*)                            \
                ((char*)&vt[bi][0] + (size_t)t * 16),                            \
            16, 0, 0);                                                           \
        __builtin_amdgcn_global_load_lds(                                        \
            (const __attribute__((address_space(1))) void*)(vsrc2 + jo_),        \
            (__attribute__((address_space(3))) void*)                            \
                ((char*)&vt[bi][0] + 16384 + (size_t)t * 16),                    \
            16, 0, 0);                                                           \
    } while (0)

    // prologue: DMA tile 0; register-prefetch ks0 A-pair for it=0
    STAGE(0, 0);
    float4 pf0 = *(const float4*)(arow);
    float4 pf1 = *(const float4*)(arow + 4);

    int cur = 0;
    for (int it = 0; it < niter; ++it) {
        __syncthreads();   // drains DMA(it) + pf loads (issued a full iter ago)

        int jt = it * JT;
        float4 c0 = pf0, c1 = pf1;                         // ks0 (ready in regs)
        float4 c2 = *(const float4*)(arow + jt + 32);      // ks1 this iter
        float4 c3 = *(const float4*)(arow + jt + 36);
        if (it + 1 < niter) {
            pf0 = *(const float4*)(arow + jt + 64);        // ks0 for it+1
            pf1 = *(const float4*)(arow + jt + 68);
            STAGE(it + 1, cur ^ 1);
        }

        const unsigned short* vb = &vt[cur][hoff];

        // ---- ks = 0 (j = jt .. jt+31) ----
        {
            float w0 = (c0.x <= thm) ? __builtin_amdgcn_exp2f(__builtin_fmaf(c0.x, cc, nmncc)) : 0.f;
            float w1 = (c0.y <= thm) ? __builtin_amdgcn_exp2f(__builtin_fmaf(c0.y, cc, nmncc)) : 0.f;
            float w2 = (c0.z <= thm) ? __builtin_amdgcn_exp2f(__builtin_fmaf(c0.z, cc, nmncc)) : 0.f;
            float w3 = (c0.w <= thm) ? __builtin_amdgcn_exp2f(__builtin_fmaf(c0.w, cc, nmncc)) : 0.f;
            float w4 = (c1.x <= thm) ? __builtin_amdgcn_exp2f(__builtin_fmaf(c1.x, cc, nmncc)) : 0.f;
            float w5 = (c1.y <= thm) ? __builtin_amdgcn_exp2f(__builtin_fmaf(c1.y, cc, nmncc)) : 0.f;
            float w6 = (c1.z <= thm) ? __builtin_amdgcn_exp2f(__builtin_fmaf(c1.z, cc, nmncc)) : 0.f;
            float w7 = (c1.w <= thm) ? __builtin_amdgcn_exp2f(__builtin_fmaf(c1.w, cc, nmncc)) : 0.f;
            zacc += ((w0 + w1) + (w2 + w3)) + ((w4 + w5) + (w6 + w7));
            union { s8v v; __hip_bfloat162 h2[4]; } afu;
            afu.h2[0] = __float22bfloat162_rn((float2){w0, w1});
            afu.h2[1] = __float22bfloat162_rn((float2){w2, w3});
            afu.h2[2] = __float22bfloat162_rn((float2){w4, w5});
            afu.h2[3] = __float22bfloat162_rn((float2){w6, w7});
            #pragma unroll
            for (int ct = 0; ct < 4; ct++) {
                int brow = ct * 16 + m16;
                s8v bf = *(const s8v*)(vb + brow * JT + bc0);
                acc[ct] = __builtin_amdgcn_mfma_f32_16x16x32_bf16(afu.v, bf, acc[ct], 0, 0, 0);
            }
        }
        // ---- ks = 1 (j = jt+32 .. jt+63) ----
        {
            float w0 = (c2.x <= thm) ? __builtin_amdgcn_exp2f(__builtin_fmaf(c2.x, cc, nmncc)) : 0.f;
            float w1 = (c2.y <= thm) ? __builtin_amdgcn_exp2f(__builtin_fmaf(c2.y, cc, nmncc)) : 0.f;
            float w2 = (c2.z <= thm) ? __builtin_amdgcn_exp2f(__builtin_fmaf(c2.z, cc, nmncc)) : 0.f;
            float w3 = (c2.w <= thm) ? __builtin_amdgcn_exp2f(__builtin_fmaf(c2.w, cc, nmncc)) : 0.f;
            float w4 = (c3.x <= thm) ? __builtin_amdgcn_exp2f(__builtin_fmaf(c3.x, cc, nmncc)) : 0.f;
            float w5 = (c3.y <= thm) ? __builtin_amdgcn_exp2f(__builtin_fmaf(c3.y, cc, nmncc)) : 0.f;
            float w6 = (c3.z <= thm) ? __builtin_amdgcn_exp2f(__builtin_fmaf(c3.z, cc, nmncc)) : 0.f;
            float w7 = (c3.w <= thm) ? __builtin_amdgcn_exp2f(__builtin_fmaf(c3.w, cc, nmncc)) : 0.f;
            zacc += ((w0 + w1) + (w2 + w3)) + ((w4 + w5) + (w6 + w7));
            union { s8v v; __hip_bfloat162 h2[4]; } afu;
            afu.h2[0] = __float22bfloat162_rn((float2){w0, w1});
            afu.h2[1] = __float22bfloat162_rn((float2){w2, w3});
            afu.h2[2] = __float22bfloat162_rn((float2){w4, w5});
            afu.h2[3] = __float22bfloat162_rn((float2){w6, w7});
            #pragma unroll
            for (int ct = 0; ct < 4; ct++) {
                int brow = ct * 16 + m16;
                s8v bf = *(const s8v*)(vb + brow * JT + bc1);
                acc[ct] = __builtin_amdgcn_mfma_f32_16x16x32_bf16(afu.v, bf, acc[ct], 0, 0, 0);
            }
        }
        cur ^= 1;
    }
    #undef STAGE

    // Z: lanes sharing m16 across q (xor 16, 32)
    zacc += __shfl_xor(zacc, 16);
    zacc += __shfl_xor(zacc, 32);
    if (q == 0)
        Zp[(((size_t)js * Bc + b) * Hc + h) * Nc + n0 + row] = zacc;

    // partial O: D row = q*4+rg (within the 16), col = ct*16+m16
    #pragma unroll
    for (int ct = 0; ct < 4; ct++) {
        #pragma unroll
        for (int rg = 0; rg < 4; rg++) {
            int nl = rq * 16 + q * 4 + rg;
            Op[(((size_t)js * Bc + b) * Nc + n0 + nl) * HIDc + h * VDc + ct * 16 + m16]
                = acc[ct][rg];
        }
    }
}

// ---------------------------------------------------------------------------
// K4: combine split-K partials, normalize, exact GELU. f32x4 per thread.
// grid = B*N*HID/1024 = 2048 blocks x 256.
// ---------------------------------------------------------------------------
__global__ __launch_bounds__(256) void combine_kernel(
    const float* __restrict__ Op, const float* __restrict__ Zp,
    float* __restrict__ out, int S)
{
    int g = blockIdx.x * 256 + threadIdx.x;       // float4 index
    int c4 = g & 63;
    int n  = (g >> 6) & (Nc - 1);
    int b  = g >> 18;                             // 64 * 4096 = 2^18
    int h  = c4 >> 4;

    float z = 0.f;
    float4 v = {0.f, 0.f, 0.f, 0.f};
    for (int s = 0; s < S; s++) {
        z += Zp[(((size_t)s * Bc + b) * Hc + h) * Nc + n];
        float4 p = *(const float4*)&Op[(((size_t)s * Bc + b) * Nc + n) * HIDc + c4 * 4];
        v.x += p.x; v.y += p.y; v.z += p.z; v.w += p.w;
    }
    float iz = 1.0f / z;
    float4 o;
    float u;
    u = v.x * iz; o.x = 0.5f * u * (1.0f + erff(u * 0.7071067811865476f));
    u = v.y * iz; o.y = 0.5f * u * (1.0f + erff(u * 0.7071067811865476f));
    u = v.z * iz; o.z = 0.5f * u * (1.0f + erff(u * 0.7071067811865476f));
    u = v.w * iz; o.w = 0.5f * u * (1.0f + erff(u * 0.7071067811865476f));
    *(float4*)&out[(((size_t)b * Nc + n) * HIDc) + c4 * 4] = o;
}

// ---------------------------------------------------------------------------
extern "C" void kernel_launch(void* const* d_in, const int* in_sizes, int n_in,
                              void* d_out, int out_size, void* d_ws, size_t ws_size,
                              hipStream_t stream) {
    const float* m_dist = (const float*)d_in[0];
    const float* x      = (const float*)d_in[1];
    const float* r      = (const float*)d_in[2];
    const float* weight = (const float*)d_in[3];
    float* out = (float*)d_out;

    char* ws = (char*)d_ws;
    const size_t MB = 1024 * 1024;
    unsigned short* vt = (unsigned short*)ws;            // 4 MiB bf16 VT
    float* thr = (float*)(ws + 4 * MB);                  // 32 KiB
    float* mn  = (float*)(ws + 4 * MB + 32 * 1024);      // 32 KiB
    float* Zp  = (float*)(ws + 4 * MB + 64 * 1024);      // up to 512 KiB
    float* Op  = (float*)(ws + 5 * MB);                  // S * 8 MiB

    const size_t OpSz = (size_t)Bc * Nc * HIDc * 4;      // 8 MiB
    // split factor: prefer 4, else 2, else 1 (needs 5MB + S*OpSz + 256KB)
    int S = 4;
    if (ws_size < 6 * MB + 4 * OpSz) S = 2;
    if (ws_size < 6 * MB + 2 * OpSz) S = 1;
    int jlen = Nc / S;

    // W hi/lo fragment buffers after Op (128 KiB each)
    char* pb = ws + 5 * MB + (size_t)S * OpSz;
    unsigned short* wh = (unsigned short*)pb;
    unsigned short* wl = (unsigned short*)(pb + 128 * 1024);

    front_kernel<<<128 + Bc * Nc, 256, 0, stream>>>(m_dist, weight, wh, wl, thr, mn);
    value_kernel<<<512, 256, 0, stream>>>(x, wh, wl, vt);
    attn_kernel<<<S * Bc * (Nc / NT), 1024, 0, stream>>>(m_dist, r, vt, thr, mn, Op, Zp, jlen);
    combine_kernel<<<(Bc * Nc * HIDc) / 1024, 256, 0, stream>>>(Op, Zp, out, S);
}

// Round 11
// 296.241 us; speedup vs baseline: 1.4008x; 1.4008x over previous
//
#include <hip/hip_runtime.h>
#include <hip/hip_bf16.h>

// Problem constants
#define Bc   2
#define Nc   4096
#define Hc   4
#define HIDc 256
#define VDc  64

typedef short s8v  __attribute__((ext_vector_type(8)));
typedef float f4v  __attribute__((ext_vector_type(4)));

static __device__ __forceinline__ unsigned short bf16bits(float f) {
    __hip_bfloat16 h = __float2bfloat16(f);
    return *(unsigned short*)&h;
}

// ---------------------------------------------------------------------------
// K1 (fused): blocks 0..127 = W-prep (bf16 hi/lo split into MFMA-A-fragment-
// linear layout); blocks 128..8319 = per-row exact 30th percentile + row min.
// Thresh: windowed histogram on [0.25,0.35] (ranks 1228/1229 of U[0,1) rows
// land there with ~7 sigma margin); exact full-range fallback if not.
// ---------------------------------------------------------------------------
__global__ __launch_bounds__(256) void front_kernel(
    const float* __restrict__ m_dist, const float* __restrict__ wgt,
    unsigned short* __restrict__ wh, unsigned short* __restrict__ wl,
    float* __restrict__ thr_out, float* __restrict__ min_out)
{
    int t = threadIdx.x, bid = blockIdx.x;

    if (bid < 128) {
        int h  = bid >> 5;
        int kt = (bid >> 3) & 3;
        int jc = bid & 7;
        int lane = t >> 2, ii = t & 3;
        #pragma unroll
        for (int u = 0; u < 2; u++) {
            int i = ii * 2 + u;
            int j = jc * 32 + (lane >> 4) * 8 + i;
            int k = kt * 16 + (lane & 15);
            float v = wgt[((size_t)h * HIDc + j) * VDc + k];
            __hip_bfloat16 hb = __float2bfloat16(v);
            float hf = __bfloat162float(hb);
            size_t o = ((((size_t)h * 4 + kt) * 8 + jc) * 64 + lane) * 8 + i;
            wh[o] = *(unsigned short*)&hb;
            wl[o] = bf16bits(v - hf);
        }
        return;
    }

    __shared__ unsigned int hist[1024];
    __shared__ float wredf[4];
    __shared__ unsigned int wsum[4];
    __shared__ unsigned int wscan[4];
    __shared__ int b0s, b1s;
    __shared__ unsigned int c0s;
    __shared__ unsigned int ncand;
    __shared__ float cand[256];
    __shared__ float s0s, s1s;

    size_t rowid = bid - 128;
    const float* row = m_dist + rowid * Nc;

    float4 vals[4];
    float lmin = 1e30f;
    #pragma unroll
    for (int i = 0; i < 4; i++) {
        float4 v = ((const float4*)row)[t + i * 256];
        vals[i] = v;
        lmin = fminf(lmin, fminf(fminf(v.x, v.y), fminf(v.z, v.w)));
    }
    #pragma unroll
    for (int o = 32; o > 0; o >>= 1) lmin = fminf(lmin, __shfl_xor(lmin, o));
    if ((t & 63) == 0) wredf[t >> 6] = lmin;

    const unsigned int R0 = 1228u, R1 = 1229u;
    float wlo = 0.25f, whi = 0.35f;
    int b0 = 0, b1 = 0;
    unsigned int C0 = 0;

    for (;;) {
        float wscale = 1024.0f / (whi - wlo);

        for (int i = t; i < 1024; i += 256) hist[i] = 0u;
        if (t == 0) ncand = 0u;
        __syncthreads();

        unsigned int cb = 0;
        #pragma unroll
        for (int i = 0; i < 4; i++) {
            float a[4] = {vals[i].x, vals[i].y, vals[i].z, vals[i].w};
            #pragma unroll
            for (int j = 0; j < 4; j++) {
                float v = a[j];
                if (v < wlo) {
                    cb++;
                } else {
                    int bx = (int)((v - wlo) * wscale);
                    if (bx < 1024) atomicAdd(&hist[bx], 1u);
                }
            }
        }
        #pragma unroll
        for (int o = 32; o > 0; o >>= 1) cb += __shfl_xor(cb, o);
        if ((t & 63) == 0) wsum[t >> 6] = cb;
        __syncthreads();
        unsigned int Cb = wsum[0] + wsum[1] + wsum[2] + wsum[3];

        unsigned int c[4], csum = 0;
        #pragma unroll
        for (int j = 0; j < 4; j++) { c[j] = hist[t * 4 + j]; csum += c[j]; }
        unsigned int inc = csum;
        #pragma unroll
        for (int o = 1; o < 64; o <<= 1) {
            unsigned int nv = __shfl_up(inc, o);
            if ((t & 63) >= o) inc += nv;
        }
        if ((t & 63) == 63) wscan[t >> 6] = inc;
        __syncthreads();
        unsigned int wpref = 0;
        for (int wv = 0; wv < (t >> 6); wv++) wpref += wscan[wv];
        unsigned int T = wscan[0] + wscan[1] + wscan[2] + wscan[3];
        unsigned int P = Cb + wpref + inc - csum;

        unsigned int cum = P;
        #pragma unroll
        for (int j = 0; j < 4; j++) {
            unsigned int lo = cum, hi = cum + c[j];
            if (R0 >= lo && R0 < hi) { b0s = t * 4 + j; c0s = lo; }
            if (R1 >= lo && R1 < hi) { b1s = t * 4 + j; }
            cum = hi;
        }
        __syncthreads();

        if (Cb <= R0 && R1 < Cb + T) { b0 = b0s; b1 = b1s; C0 = c0s; break; }
        wlo = 0.0f; whi = 1.001f;
    }

    float wscale = 1024.0f / (whi - wlo);
    #pragma unroll
    for (int i = 0; i < 4; i++) {
        float a[4] = {vals[i].x, vals[i].y, vals[i].z, vals[i].w};
        #pragma unroll
        for (int j = 0; j < 4; j++) {
            float v = a[j];
            if (v >= wlo) {
                int bx = (int)((v - wlo) * wscale);
                if (bx >= b0 && bx <= b1) {
                    unsigned int p = atomicAdd(&ncand, 1u);
                    if (p < 256u) cand[p] = v;
                }
            }
        }
    }
    __syncthreads();
    unsigned int nc = min(ncand, 256u);
    if ((unsigned int)t < nc) {
        float v = cand[t];
        unsigned int rk = C0;
        for (unsigned int j = 0; j < nc; j++) {
            float u = cand[j];
            rk += (u < v || (u == v && j < (unsigned int)t)) ? 1u : 0u;
        }
        if (rk == R0) s0s = v;
        if (rk == R1) s1s = v;
    }
    __syncthreads();
    if (t == 0) {
        thr_out[rowid] = 0.5f * (s0s + s1s);
        min_out[rowid] = fminf(fminf(wredf[0], wredf[1]), fminf(wredf[2], wredf[3]));
    }
}

// ---------------------------------------------------------------------------
// K2: V^T via MFMA, 3-term bf16 split (Ah*Bh + Al*Bh + Ah*Bl ~ f32-accurate).
// x converted f32 -> bf16 hi/lo inline. VT[b,h,k,n] bf16 directly.
// grid = B*H*(N/64) = 512 blocks x 256 (4 waves; wave w owns n-subtile w).
// ---------------------------------------------------------------------------
__global__ __launch_bounds__(256) void value_kernel(
    const float* __restrict__ x,
    const unsigned short* __restrict__ wh, const unsigned short* __restrict__ wl,
    unsigned short* __restrict__ vt_g)
{
    int t  = threadIdx.x;
    int bid = blockIdx.x;
    int nt = bid & 63;
    int h  = (bid >> 6) & 3;
    int b  = bid >> 8;
    int n0 = nt * 64;

    int w = t >> 6, lane = t & 63, q4 = lane >> 4, m16 = lane & 15;
    int nb = n0 + w * 16;

    const float* xp = x + ((size_t)(b * Nc + nb + m16)) * HIDc + q4 * 8;

    f4v acc[4];
    #pragma unroll
    for (int kt = 0; kt < 4; kt++) acc[kt] = (f4v){0.f, 0.f, 0.f, 0.f};

    #pragma unroll
    for (int jc = 0; jc < 8; jc++) {
        float4 xv0 = *(const float4*)(xp + jc * 32);
        float4 xv1 = *(const float4*)(xp + jc * 32 + 4);
        float f[8] = {xv0.x, xv0.y, xv0.z, xv0.w, xv1.x, xv1.y, xv1.z, xv1.w};
        union { s8v v; unsigned short u[8]; } hs, ls;
        #pragma unroll
        for (int i = 0; i < 8; i++) {
            __hip_bfloat16 hb = __float2bfloat16(f[i]);
            float hf = __bfloat162float(hb);
            hs.u[i] = *(unsigned short*)&hb;
            ls.u[i] = bf16bits(f[i] - hf);
        }
        #pragma unroll
        for (int kt = 0; kt < 4; kt++) {
            size_t ao = (((size_t)(h * 4 + kt) * 8 + jc) << 9) + lane * 8;
            s8v ah = *(const s8v*)(wh + ao);
            s8v al = *(const s8v*)(wl + ao);
            acc[kt] = __builtin_amdgcn_mfma_f32_16x16x32_bf16(ah, hs.v, acc[kt], 0, 0, 0);
            acc[kt] = __builtin_amdgcn_mfma_f32_16x16x32_bf16(al, hs.v, acc[kt], 0, 0, 0);
            acc[kt] = __builtin_amdgcn_mfma_f32_16x16x32_bf16(ah, ls.v, acc[kt], 0, 0, 0);
        }
    }

    unsigned short* vg = vt_g + (((size_t)b * Hc + h) * VDc) * Nc;
    #pragma unroll
    for (int kt = 0; kt < 4; kt++) {
        #pragma unroll
        for (int rg = 0; rg < 4; rg++) {
            int k = kt * 16 + q4 * 4 + rg;
            vg[(size_t)k * Nc + nb + m16] = bf16bits(acc[kt][rg]);
        }
    }
}

// ---------------------------------------------------------------------------
// K3: fused mask + softmax-numerator + PV (bf16 MFMA), split-K over j.
// R11 = R10 minus the SPILLER. R10's counters split the two changes cleanly:
//  - JT=64 conflict-free B layout: SQ_LDS_BANK_CONFLICT 4.19M -> 0. KEEP.
//  - A-register-prefetch: pushed live regs past the 64-VGPR (1024,8) cap ->
//    scratch spill (WRITE_SIZE 33MB -> 384MB, ~130us of scratch traffic).
//    REMOVED: all four A float4s load at compute head (R9 style; JT=32 R9
//    ran 28 VGPR spill-free, JT=64 adds ~8 live f32s -> ~48 VGPR, under cap).
// STAGE issues after the A-loads so the 2 DMAs stay in flight across the
// barrier-adjacent waits. Double-buffered vt (2x32KB, 2 blocks/CU); ONE
// barrier per 64-j iteration (16 total; R8 had 32); premask inline.
// Numerics: per-element formulas, MFMA j-order, reduction trees identical
// to R8/R9/R10 -> bit-identical output (absmax change = regression canary).
// ---------------------------------------------------------------------------
#define NT 64
#define JT 64

__global__ __launch_bounds__(1024, 8) void attn_kernel(
    const float* __restrict__ m_dist, const float* __restrict__ rr,
    const unsigned short* __restrict__ vt_g,
    const float* __restrict__ thr_g, const float* __restrict__ min_g,
    float* __restrict__ Op, float* __restrict__ Zp, int jlen)
{
    __shared__ unsigned short vt[2][Hc * VDc * JT];   // 2 x 32 KB

    int t = threadIdx.x;
    const int nblk = Bc * (Nc / NT);        // 128
    int js = blockIdx.x / nblk;
    int rb = blockIdx.x - js * nblk;
    int b  = rb >> 6;                       // Nc/NT = 64 row-tiles
    int n0 = (rb & 63) * NT;
    int j0 = js * jlen;

    int lane = t & 63, q = lane >> 4, m16 = lane & 15;
    int w = t >> 6;                         // wave 0..15
    int h = w & 3, rq = w >> 2;             // head, row-quad
    int row = rq * 16 + m16;                // local A-row this lane owns (0..63)

    float mn  = min_g[b * Nc + n0 + row];
    float thm = thr_g[b * Nc + n0 + row];
    float rv = rr[h];
    float cc = -(rv * rv) * 1.4426950408889634f;   // -r^2 * log2(e)
    float nmncc = -mn * cc;                        // w = exp2(fma(d, cc, nmncc))

    f4v acc[4];
    #pragma unroll
    for (int ct = 0; ct < 4; ct++) acc[ct] = (f4v){0.f, 0.f, 0.f, 0.f};
    float zacc = 0.f;

    // per-lane direct A source: m_dist[b][n0+row][j0 + q*8 + ...]
    const float* arow = m_dist + ((size_t)b * Nc + n0 + row) * Nc + j0 + q * 8;

    // vt DMA staging (2 DMAs/thread): row r = (t>>3) + i*128 (128B rows),
    // phys 16B-chunk t&7, logical source chunk (t&7)^(r&7), r&7 == (t>>3)&7.
    // LDS dest linear = i*16KB + t*16 B (wave-uniform base + lane*16).
    const unsigned short* vtb = vt_g + ((size_t)b * Hc * VDc) * Nc + j0;
    const unsigned short* vsrc  = vtb + (size_t)(t >> 3) * Nc + (((t & 7) ^ ((t >> 3) & 7)) << 3);
    const unsigned short* vsrc2 = vsrc + (size_t)128 * Nc;

    // B-read swizzled chunk offsets (ushorts within 64-ushort row)
    int bc0 = ((q ^ (m16 & 7)) << 3);        // ks=0: logical chunk q
    int bc1 = (((4 + q) ^ (m16 & 7)) << 3);  // ks=1: logical chunk 4+q
    const int hoff = h * VDc * JT;

    int niter = jlen / JT;                   // 16

    #define STAGE(k, bi) do {                                                    \
        size_t jo_ = (size_t)(k) * JT;                                           \
        __builtin_amdgcn_global_load_lds(                                        \
            (const __attribute__((address_space(1))) void*)(vsrc + jo_),         \
            (__attribute__((address_space(3))) void*)                            \
                ((char*)&vt[bi][0] + (size_t)t * 16),                            \
            16, 0, 0);                                                           \
        __builtin_amdgcn_global_load_lds(                                        \
            (const __attribute__((address_space(1))) void*)(vsrc2 + jo_),        \
            (__attribute__((address_space(3))) void*)                            \
                ((char*)&vt[bi][0] + 16384 + (size_t)t * 16),                    \
            16, 0, 0);                                                           \
    } while (0)

    // prologue: DMA tile 0
    STAGE(0, 0);

    int cur = 0;
    for (int it = 0; it < niter; ++it) {
        __syncthreads();   // drains DMA(it); buf cur^1 free for it+1

        int jt = it * JT;
        // A loads for this iteration (L3/L1); issued before STAGE so the
        // compiler's dependency-exact waitcnt leaves the DMAs in flight.
        float4 c0 = *(const float4*)(arow + jt);
        float4 c1 = *(const float4*)(arow + jt + 4);
        float4 c2 = *(const float4*)(arow + jt + 32);
        float4 c3 = *(const float4*)(arow + jt + 36);
        if (it + 1 < niter) STAGE(it + 1, cur ^ 1);

        const unsigned short* vb = &vt[cur][hoff];

        // ---- ks = 0 (j = jt .. jt+31) ----
        {
            float w0 = (c0.x <= thm) ? __builtin_amdgcn_exp2f(__builtin_fmaf(c0.x, cc, nmncc)) : 0.f;
            float w1 = (c0.y <= thm) ? __builtin_amdgcn_exp2f(__builtin_fmaf(c0.y, cc, nmncc)) : 0.f;
            float w2 = (c0.z <= thm) ? __builtin_amdgcn_exp2f(__builtin_fmaf(c0.z, cc, nmncc)) : 0.f;
            float w3 = (c0.w <= thm) ? __builtin_amdgcn_exp2f(__builtin_fmaf(c0.w, cc, nmncc)) : 0.f;
            float w4 = (c1.x <= thm) ? __builtin_amdgcn_exp2f(__builtin_fmaf(c1.x, cc, nmncc)) : 0.f;
            float w5 = (c1.y <= thm) ? __builtin_amdgcn_exp2f(__builtin_fmaf(c1.y, cc, nmncc)) : 0.f;
            float w6 = (c1.z <= thm) ? __builtin_amdgcn_exp2f(__builtin_fmaf(c1.z, cc, nmncc)) : 0.f;
            float w7 = (c1.w <= thm) ? __builtin_amdgcn_exp2f(__builtin_fmaf(c1.w, cc, nmncc)) : 0.f;
            zacc += ((w0 + w1) + (w2 + w3)) + ((w4 + w5) + (w6 + w7));
            union { s8v v; __hip_bfloat162 h2[4]; } afu;
            afu.h2[0] = __float22bfloat162_rn((float2){w0, w1});
            afu.h2[1] = __float22bfloat162_rn((float2){w2, w3});
            afu.h2[2] = __float22bfloat162_rn((float2){w4, w5});
            afu.h2[3] = __float22bfloat162_rn((float2){w6, w7});
            #pragma unroll
            for (int ct = 0; ct < 4; ct++) {
                int brow = ct * 16 + m16;
                s8v bf = *(const s8v*)(vb + brow * JT + bc0);
                acc[ct] = __builtin_amdgcn_mfma_f32_16x16x32_bf16(afu.v, bf, acc[ct], 0, 0, 0);
            }
        }
        // ---- ks = 1 (j = jt+32 .. jt+63) ----
        {
            float w0 = (c2.x <= thm) ? __builtin_amdgcn_exp2f(__builtin_fmaf(c2.x, cc, nmncc)) : 0.f;
            float w1 = (c2.y <= thm) ? __builtin_amdgcn_exp2f(__builtin_fmaf(c2.y, cc, nmncc)) : 0.f;
            float w2 = (c2.z <= thm) ? __builtin_amdgcn_exp2f(__builtin_fmaf(c2.z, cc, nmncc)) : 0.f;
            float w3 = (c2.w <= thm) ? __builtin_amdgcn_exp2f(__builtin_fmaf(c2.w, cc, nmncc)) : 0.f;
            float w4 = (c3.x <= thm) ? __builtin_amdgcn_exp2f(__builtin_fmaf(c3.x, cc, nmncc)) : 0.f;
            float w5 = (c3.y <= thm) ? __builtin_amdgcn_exp2f(__builtin_fmaf(c3.y, cc, nmncc)) : 0.f;
            float w6 = (c3.z <= thm) ? __builtin_amdgcn_exp2f(__builtin_fmaf(c3.z, cc, nmncc)) : 0.f;
            float w7 = (c3.w <= thm) ? __builtin_amdgcn_exp2f(__builtin_fmaf(c3.w, cc, nmncc)) : 0.f;
            zacc += ((w0 + w1) + (w2 + w3)) + ((w4 + w5) + (w6 + w7));
            union { s8v v; __hip_bfloat162 h2[4]; } afu;
            afu.h2[0] = __float22bfloat162_rn((float2){w0, w1});
            afu.h2[1] = __float22bfloat162_rn((float2){w2, w3});
            afu.h2[2] = __float22bfloat162_rn((float2){w4, w5});
            afu.h2[3] = __float22bfloat162_rn((float2){w6, w7});
            #pragma unroll
            for (int ct = 0; ct < 4; ct++) {
                int brow = ct * 16 + m16;
                s8v bf = *(const s8v*)(vb + brow * JT + bc1);
                acc[ct] = __builtin_amdgcn_mfma_f32_16x16x32_bf16(afu.v, bf, acc[ct], 0, 0, 0);
            }
        }
        cur ^= 1;
    }
    #undef STAGE

    // Z: lanes sharing m16 across q (xor 16, 32)
    zacc += __shfl_xor(zacc, 16);
    zacc += __shfl_xor(zacc, 32);
    if (q == 0)
        Zp[(((size_t)js * Bc + b) * Hc + h) * Nc + n0 + row] = zacc;

    // partial O: D row = q*4+rg (within the 16), col = ct*16+m16
    #pragma unroll
    for (int ct = 0; ct < 4; ct++) {
        #pragma unroll
        for (int rg = 0; rg < 4; rg++) {
            int nl = rq * 16 + q * 4 + rg;
            Op[(((size_t)js * Bc + b) * Nc + n0 + nl) * HIDc + h * VDc + ct * 16 + m16]
                = acc[ct][rg];
        }
    }
}

// ---------------------------------------------------------------------------
// K4: combine split-K partials, normalize, exact GELU. f32x4 per thread.
// grid = B*N*HID/1024 = 2048 blocks x 256.
// ---------------------------------------------------------------------------
__global__ __launch_bounds__(256) void combine_kernel(
    const float* __restrict__ Op, const float* __restrict__ Zp,
    float* __restrict__ out, int S)
{
    int g = blockIdx.x * 256 + threadIdx.x;       // float4 index
    int c4 = g & 63;
    int n  = (g >> 6) & (Nc - 1);
    int b  = g >> 18;                             // 64 * 4096 = 2^18
    int h  = c4 >> 4;

    float z = 0.f;
    float4 v = {0.f, 0.f, 0.f, 0.f};
    for (int s = 0; s < S; s++) {
        z += Zp[(((size_t)s * Bc + b) * Hc + h) * Nc + n];
        float4 p = *(const float4*)&Op[(((size_t)s * Bc + b) * Nc + n) * HIDc + c4 * 4];
        v.x += p.x; v.y += p.y; v.z += p.z; v.w += p.w;
    }
    float iz = 1.0f / z;
    float4 o;
    float u;
    u = v.x * iz; o.x = 0.5f * u * (1.0f + erff(u * 0.7071067811865476f));
    u = v.y * iz; o.y = 0.5f * u * (1.0f + erff(u * 0.7071067811865476f));
    u = v.z * iz; o.z = 0.5f * u * (1.0f + erff(u * 0.7071067811865476f));
    u = v.w * iz; o.w = 0.5f * u * (1.0f + erff(u * 0.7071067811865476f));
    *(float4*)&out[(((size_t)b * Nc + n) * HIDc) + c4 * 4] = o;
}

// ---------------------------------------------------------------------------
extern "C" void kernel_launch(void* const* d_in, const int* in_sizes, int n_in,
                              void* d_out, int out_size, void* d_ws, size_t ws_size,
                              hipStream_t stream) {
    const float* m_dist = (const float*)d_in[0];
    const float* x      = (const float*)d_in[1];
    const float* r      = (const float*)d_in[2];
    const float* weight = (const float*)d_in[3];
    float* out = (float*)d_out;

    char* ws = (char*)d_ws;
    const size_t MB = 1024 * 1024;
    unsigned short* vt = (unsigned short*)ws;            // 4 MiB bf16 VT
    float* thr = (float*)(ws + 4 * MB);                  // 32 KiB
    float* mn  = (float*)(ws + 4 * MB + 32 * 1024);      // 32 KiB
    float* Zp  = (float*)(ws + 4 * MB + 64 * 1024);      // up to 512 KiB
    float* Op  = (float*)(ws + 5 * MB);                  // S * 8 MiB

    const size_t OpSz = (size_t)Bc * Nc * HIDc * 4;      // 8 MiB
    // split factor: prefer 4, else 2, else 1 (needs 5MB + S*OpSz + 256KB)
    int S = 4;
    if (ws_size < 6 * MB + 4 * OpSz) S = 2;
    if (ws_size < 6 * MB + 2 * OpSz) S = 1;
    int jlen = Nc / S;

    // W hi/lo fragment buffers after Op (128 KiB each)
    char* pb = ws + 5 * MB + (size_t)S * OpSz;
    unsigned short* wh = (unsigned short*)pb;
    unsigned short* wl = (unsigned short*)(pb + 128 * 1024);

    front_kernel<<<128 + Bc * Nc, 256, 0, stream>>>(m_dist, weight, wh, wl, thr, mn);
    value_kernel<<<512, 256, 0, stream>>>(x, wh, wl, vt);
    attn_kernel<<<S * Bc * (Nc / NT), 1024, 0, stream>>>(m_dist, r, vt, thr, mn, Op, Zp, jlen);
    combine_kernel<<<(Bc * Nc * HIDc) / 1024, 256, 0, stream>>>(Op, Zp, out, S);
}

// Round 12
// 260.637 us; speedup vs baseline: 1.5921x; 1.1366x over previous
//
#include <hip/hip_runtime.h>
#include <hip/hip_bf16.h>

// Problem constants
#define Bc   2
#define Nc   4096
#define Hc   4
#define HIDc 256
#define VDc  64

typedef short s8v  __attribute__((ext_vector_type(8)));
typedef float f4v  __attribute__((ext_vector_type(4)));

static __device__ __forceinline__ unsigned short bf16bits(float f) {
    __hip_bfloat16 h = __float2bfloat16(f);
    return *(unsigned short*)&h;
}

// ---------------------------------------------------------------------------
// K1 (fused): blocks 0..127 = W-prep (bf16 hi/lo split into MFMA-A-fragment-
// linear layout); blocks 128..8319 = per-row exact 30th percentile + row min.
// Thresh: windowed histogram on [0.25,0.35] (ranks 1228/1229 of U[0,1) rows
// land there with ~7 sigma margin); exact full-range fallback if not.
// ---------------------------------------------------------------------------
__global__ __launch_bounds__(256) void front_kernel(
    const float* __restrict__ m_dist, const float* __restrict__ wgt,
    unsigned short* __restrict__ wh, unsigned short* __restrict__ wl,
    float* __restrict__ thr_out, float* __restrict__ min_out)
{
    int t = threadIdx.x, bid = blockIdx.x;

    if (bid < 128) {
        int h  = bid >> 5;
        int kt = (bid >> 3) & 3;
        int jc = bid & 7;
        int lane = t >> 2, ii = t & 3;
        #pragma unroll
        for (int u = 0; u < 2; u++) {
            int i = ii * 2 + u;
            int j = jc * 32 + (lane >> 4) * 8 + i;
            int k = kt * 16 + (lane & 15);
            float v = wgt[((size_t)h * HIDc + j) * VDc + k];
            __hip_bfloat16 hb = __float2bfloat16(v);
            float hf = __bfloat162float(hb);
            size_t o = ((((size_t)h * 4 + kt) * 8 + jc) * 64 + lane) * 8 + i;
            wh[o] = *(unsigned short*)&hb;
            wl[o] = bf16bits(v - hf);
        }
        return;
    }

    __shared__ unsigned int hist[1024];
    __shared__ float wredf[4];
    __shared__ unsigned int wsum[4];
    __shared__ unsigned int wscan[4];
    __shared__ int b0s, b1s;
    __shared__ unsigned int c0s;
    __shared__ unsigned int ncand;
    __shared__ float cand[256];
    __shared__ float s0s, s1s;

    size_t rowid = bid - 128;
    const float* row = m_dist + rowid * Nc;

    float4 vals[4];
    float lmin = 1e30f;
    #pragma unroll
    for (int i = 0; i < 4; i++) {
        float4 v = ((const float4*)row)[t + i * 256];
        vals[i] = v;
        lmin = fminf(lmin, fminf(fminf(v.x, v.y), fminf(v.z, v.w)));
    }
    #pragma unroll
    for (int o = 32; o > 0; o >>= 1) lmin = fminf(lmin, __shfl_xor(lmin, o));
    if ((t & 63) == 0) wredf[t >> 6] = lmin;

    const unsigned int R0 = 1228u, R1 = 1229u;
    float wlo = 0.25f, whi = 0.35f;
    int b0 = 0, b1 = 0;
    unsigned int C0 = 0;

    for (;;) {
        float wscale = 1024.0f / (whi - wlo);

        for (int i = t; i < 1024; i += 256) hist[i] = 0u;
        if (t == 0) ncand = 0u;
        __syncthreads();

        unsigned int cb = 0;
        #pragma unroll
        for (int i = 0; i < 4; i++) {
            float a[4] = {vals[i].x, vals[i].y, vals[i].z, vals[i].w};
            #pragma unroll
            for (int j = 0; j < 4; j++) {
                float v = a[j];
                if (v < wlo) {
                    cb++;
                } else {
                    int bx = (int)((v - wlo) * wscale);
                    if (bx < 1024) atomicAdd(&hist[bx], 1u);
                }
            }
        }
        #pragma unroll
        for (int o = 32; o > 0; o >>= 1) cb += __shfl_xor(cb, o);
        if ((t & 63) == 0) wsum[t >> 6] = cb;
        __syncthreads();
        unsigned int Cb = wsum[0] + wsum[1] + wsum[2] + wsum[3];

        unsigned int c[4], csum = 0;
        #pragma unroll
        for (int j = 0; j < 4; j++) { c[j] = hist[t * 4 + j]; csum += c[j]; }
        unsigned int inc = csum;
        #pragma unroll
        for (int o = 1; o < 64; o <<= 1) {
            unsigned int nv = __shfl_up(inc, o);
            if ((t & 63) >= o) inc += nv;
        }
        if ((t & 63) == 63) wscan[t >> 6] = inc;
        __syncthreads();
        unsigned int wpref = 0;
        for (int wv = 0; wv < (t >> 6); wv++) wpref += wscan[wv];
        unsigned int T = wscan[0] + wscan[1] + wscan[2] + wscan[3];
        unsigned int P = Cb + wpref + inc - csum;

        unsigned int cum = P;
        #pragma unroll
        for (int j = 0; j < 4; j++) {
            unsigned int lo = cum, hi = cum + c[j];
            if (R0 >= lo && R0 < hi) { b0s = t * 4 + j; c0s = lo; }
            if (R1 >= lo && R1 < hi) { b1s = t * 4 + j; }
            cum = hi;
        }
        __syncthreads();

        if (Cb <= R0 && R1 < Cb + T) { b0 = b0s; b1 = b1s; C0 = c0s; break; }
        wlo = 0.0f; whi = 1.001f;
    }

    float wscale = 1024.0f / (whi - wlo);
    #pragma unroll
    for (int i = 0; i < 4; i++) {
        float a[4] = {vals[i].x, vals[i].y, vals[i].z, vals[i].w};
        #pragma unroll
        for (int j = 0; j < 4; j++) {
            float v = a[j];
            if (v >= wlo) {
                int bx = (int)((v - wlo) * wscale);
                if (bx >= b0 && bx <= b1) {
                    unsigned int p = atomicAdd(&ncand, 1u);
                    if (p < 256u) cand[p] = v;
                }
            }
        }
    }
    __syncthreads();
    unsigned int nc = min(ncand, 256u);
    if ((unsigned int)t < nc) {
        float v = cand[t];
        unsigned int rk = C0;
        for (unsigned int j = 0; j < nc; j++) {
            float u = cand[j];
            rk += (u < v || (u == v && j < (unsigned int)t)) ? 1u : 0u;
        }
        if (rk == R0) s0s = v;
        if (rk == R1) s1s = v;
    }
    __syncthreads();
    if (t == 0) {
        thr_out[rowid] = 0.5f * (s0s + s1s);
        min_out[rowid] = fminf(fminf(wredf[0], wredf[1]), fminf(wredf[2], wredf[3]));
    }
}

// ---------------------------------------------------------------------------
// K2: V^T via MFMA, 3-term bf16 split (Ah*Bh + Al*Bh + Ah*Bl ~ f32-accurate).
// x converted f32 -> bf16 hi/lo inline. VT[b,h,k,n] bf16 directly.
// grid = B*H*(N/64) = 512 blocks x 256 (4 waves; wave w owns n-subtile w).
// ---------------------------------------------------------------------------
__global__ __launch_bounds__(256) void value_kernel(
    const float* __restrict__ x,
    const unsigned short* __restrict__ wh, const unsigned short* __restrict__ wl,
    unsigned short* __restrict__ vt_g)
{
    int t  = threadIdx.x;
    int bid = blockIdx.x;
    int nt = bid & 63;
    int h  = (bid >> 6) & 3;
    int b  = bid >> 8;
    int n0 = nt * 64;

    int w = t >> 6, lane = t & 63, q4 = lane >> 4, m16 = lane & 15;
    int nb = n0 + w * 16;

    const float* xp = x + ((size_t)(b * Nc + nb + m16)) * HIDc + q4 * 8;

    f4v acc[4];
    #pragma unroll
    for (int kt = 0; kt < 4; kt++) acc[kt] = (f4v){0.f, 0.f, 0.f, 0.f};

    #pragma unroll
    for (int jc = 0; jc < 8; jc++) {
        float4 xv0 = *(const float4*)(xp + jc * 32);
        float4 xv1 = *(const float4*)(xp + jc * 32 + 4);
        float f[8] = {xv0.x, xv0.y, xv0.z, xv0.w, xv1.x, xv1.y, xv1.z, xv1.w};
        union { s8v v; unsigned short u[8]; } hs, ls;
        #pragma unroll
        for (int i = 0; i < 8; i++) {
            __hip_bfloat16 hb = __float2bfloat16(f[i]);
            float hf = __bfloat162float(hb);
            hs.u[i] = *(unsigned short*)&hb;
            ls.u[i] = bf16bits(f[i] - hf);
        }
        #pragma unroll
        for (int kt = 0; kt < 4; kt++) {
            size_t ao = (((size_t)(h * 4 + kt) * 8 + jc) << 9) + lane * 8;
            s8v ah = *(const s8v*)(wh + ao);
            s8v al = *(const s8v*)(wl + ao);
            acc[kt] = __builtin_amdgcn_mfma_f32_16x16x32_bf16(ah, hs.v, acc[kt], 0, 0, 0);
            acc[kt] = __builtin_amdgcn_mfma_f32_16x16x32_bf16(al, hs.v, acc[kt], 0, 0, 0);
            acc[kt] = __builtin_amdgcn_mfma_f32_16x16x32_bf16(ah, ls.v, acc[kt], 0, 0, 0);
        }
    }

    unsigned short* vg = vt_g + (((size_t)b * Hc + h) * VDc) * Nc;
    #pragma unroll
    for (int kt = 0; kt < 4; kt++) {
        #pragma unroll
        for (int rg = 0; rg < 4; rg++) {
            int k = kt * 16 + q4 * 4 + rg;
            vg[(size_t)k * Nc + nb + m16] = bf16bits(acc[kt][rg]);
        }
    }
}

// ---------------------------------------------------------------------------
// K3: fused mask + softmax-numerator + PV (bf16 MFMA), split-K over j.
// R12 = R8 VERBATIM except vt's LDS geometry: PAIR-ROW layout.
// R8/R9/R11 isolated the factors: A must stay on R8's pipelined staging path
// (global-in-compute = +13us, R11); R8's only measured defect is the vt
// 4-way bank conflict (4.19M cycles on the identical layout, R9).
// Pair-row fix: pair p = k>>1 is one 128B row [k-even | k-odd]; 16B chunk
// swizzle c_phys = c_log ^ (p&3). Per 16-lane read phase the B-read touches
// (m16&1) half-rows x 4 swizzled chunks = 8 distinct 16B slots, 2 lanes each
// -> 2-way = free (the property that measured 0 conflicts in R10/R11).
// DMA keeps the linear dest (t*16B); only the per-thread SOURCE index is
// re-permuted (bijection on (k,chunk) per head). Same 48KB LDS, same
// barriers, same A-path, same numerics -> bit-identical output.
// ---------------------------------------------------------------------------
#define NT 64
#define JT 32
#define BIGF 3.0e38f

__global__ __launch_bounds__(1024, 8) void attn_kernel(
    const float* __restrict__ m_dist, const float* __restrict__ rr,
    const unsigned short* __restrict__ vt_g,
    const float* __restrict__ thr_g, const float* __restrict__ min_g,
    float* __restrict__ Op, float* __restrict__ Zp, int jlen)
{
    __shared__ float ms[2][NT * JT];                  // 2 x 8 KB, f4-chunk c at c^(row&7)
    __shared__ unsigned short vt[2][Hc * VDc * JT];   // 2 x 16 KB, pair-row layout

    int t = threadIdx.x;
    const int nblk = Bc * (Nc / NT);        // 128
    int js = blockIdx.x / nblk;
    int rb = blockIdx.x - js * nblk;
    int b  = rb >> 6;                       // Nc/NT = 64 row-tiles
    int n0 = (rb & 63) * NT;
    int j0 = js * jlen;

    int lane = t & 63, q = lane >> 4, m16 = lane & 15;
    int w = t >> 6;                         // wave 0..15
    int h = w & 3, rq = w >> 2;             // head, row-quad
    int row = rq * 16 + m16;                // local A-row this lane owns (0..63)

    float mn = min_g[b * Nc + n0 + row];
    float rv = rr[h];
    float cc = -(rv * rv) * 1.4426950408889634f;   // -r^2 * log2(e)
    float nmncc = -mn * cc;                        // w = exp2(fma(d, cc, nmncc))

    f4v acc[4];
    #pragma unroll
    for (int ct = 0; ct < 4; ct++) acc[ct] = (f4v){0.f, 0.f, 0.f, 0.f};
    float zacc = 0.f;

    const float* mbase = m_dist + ((size_t)b * Nc + n0) * Nc + j0;
    const unsigned short* vtb = vt_g + ((size_t)b * Hc * VDc) * Nc + j0;

    // ms staging (threads 0..511 / waves 0..7): row t>>3, logical f4-chunk t&7
    int mrow = t >> 3, mch = t & 7;
    int msw  = mrow * JT + ((mch ^ (mrow & 7)) << 2);
    const float* msrc = mbase + (size_t)mrow * Nc + mch * 4;
    float thm = (t < 512) ? thr_g[b * Nc + n0 + mrow] : 0.f;

    // vt DMA staging, PAIR-ROW layout (all 1024 threads, 1 DMA each):
    //   t = h_s*256 + p_s*8 + (k&1)*4 + c_phys  (LDS dest linear = t*16 B)
    //   k_s = 2*p_s + ((t>>2)&1);  c_log = c_phys ^ (p_s & 3)
    {
        // computed once; folded into vsrc below
    }
    int h_s   = t >> 8;
    int p_s   = (t >> 3) & 31;
    int k_s   = (p_s << 1) | ((t >> 2) & 1);
    int c_log = (t & 3) ^ (p_s & 3);
    const unsigned short* vsrc = vtb + ((size_t)(h_s * VDc + k_s)) * Nc + c_log * 8;

    // A-read swizzled f4-chunk offsets (row&7 == m16&7)
    int s7 = m16 & 7;
    int a0o = row * JT + (((q * 2 + 0) ^ s7) << 2);
    int a1o = row * JT + (((q * 2 + 1) ^ s7) << 2);
    // B-read, pair-row layout: ushort offset within head tile for (ct, lane):
    //   p = ct*8 + (m16>>1);  off = p*64 + (m16&1)*32 + (q ^ (p&3))*8
    //   (p&3 == (m16>>1)&3 since ct*8 ≡ 0 mod 4)
    int bco = ((m16 >> 1) << 6) + ((m16 & 1) << 5) + ((q ^ ((m16 >> 1) & 3)) << 3);

    int niter = jlen / JT;

    // prologue: issue loads for it=0
    float4 msreg;
    if (t < 512) msreg = *(const float4*)(msrc);
    __builtin_amdgcn_global_load_lds(
        (const __attribute__((address_space(1))) void*)(vsrc),
        (__attribute__((address_space(3))) void*)(&vt[0][(size_t)t * 8]),
        16, 0, 0);

    int cur = 0;
    for (int it = 0; it < niter; ++it) {
        // write ms(it) into buf cur (premask; masked d -> 3e38 so exp2 -> 0)
        if (t < 512) {
            float4 v = msreg;
            v.x = (v.x <= thm) ? v.x : BIGF;
            v.y = (v.y <= thm) ? v.y : BIGF;
            v.z = (v.z <= thm) ? v.z : BIGF;
            v.w = (v.w <= thm) ? v.w : BIGF;
            *(float4*)&ms[cur][msw] = v;
        }
        __syncthreads();   // vt(it) DMA drained + ms(it) visible; buf cur^1 free

        // issue loads for it+1 into buf cur^1 (complete under compute below)
        if (it + 1 < niter) {
            int jn = (it + 1) * JT;
            if (t < 512) msreg = *(const float4*)(msrc + jn);
            __builtin_amdgcn_global_load_lds(
                (const __attribute__((address_space(1))) void*)(vsrc + jn),
                (__attribute__((address_space(3))) void*)(&vt[cur ^ 1][(size_t)t * 8]),
                16, 0, 0);
        }

        // compute(it) from buf cur
        const unsigned short* vb = &vt[cur][h * VDc * JT];
        float4 a0 = *(const float4*)&ms[cur][a0o];
        float4 a1 = *(const float4*)&ms[cur][a1o];
        float w0 = __builtin_amdgcn_exp2f(__builtin_fmaf(a0.x, cc, nmncc));
        float w1 = __builtin_amdgcn_exp2f(__builtin_fmaf(a0.y, cc, nmncc));
        float w2 = __builtin_amdgcn_exp2f(__builtin_fmaf(a0.z, cc, nmncc));
        float w3 = __builtin_amdgcn_exp2f(__builtin_fmaf(a0.w, cc, nmncc));
        float w4 = __builtin_amdgcn_exp2f(__builtin_fmaf(a1.x, cc, nmncc));
        float w5 = __builtin_amdgcn_exp2f(__builtin_fmaf(a1.y, cc, nmncc));
        float w6 = __builtin_amdgcn_exp2f(__builtin_fmaf(a1.z, cc, nmncc));
        float w7 = __builtin_amdgcn_exp2f(__builtin_fmaf(a1.w, cc, nmncc));
        zacc += ((w0 + w1) + (w2 + w3)) + ((w4 + w5) + (w6 + w7));
        union { s8v v; __hip_bfloat162 h2[4]; } afu;
        afu.h2[0] = __float22bfloat162_rn((float2){w0, w1});
        afu.h2[1] = __float22bfloat162_rn((float2){w2, w3});
        afu.h2[2] = __float22bfloat162_rn((float2){w4, w5});
        afu.h2[3] = __float22bfloat162_rn((float2){w6, w7});
        #pragma unroll
        for (int ct = 0; ct < 4; ct++) {
            s8v bf = *(const s8v*)(vb + ct * 512 + bco);
            acc[ct] = __builtin_amdgcn_mfma_f32_16x16x32_bf16(afu.v, bf, acc[ct], 0, 0, 0);
        }
        cur ^= 1;
    }

    // Z: lanes sharing m16 across q (xor 16, 32)
    zacc += __shfl_xor(zacc, 16);
    zacc += __shfl_xor(zacc, 32);
    if (q == 0)
        Zp[(((size_t)js * Bc + b) * Hc + h) * Nc + n0 + row] = zacc;

    // partial O: D row = q*4+rg (within the 16), col = ct*16+m16
    #pragma unroll
    for (int ct = 0; ct < 4; ct++) {
        #pragma unroll
        for (int rg = 0; rg < 4; rg++) {
            int nl = rq * 16 + q * 4 + rg;
            Op[(((size_t)js * Bc + b) * Nc + n0 + nl) * HIDc + h * VDc + ct * 16 + m16]
                = acc[ct][rg];
        }
    }
}

// ---------------------------------------------------------------------------
// K4: combine split-K partials, normalize, exact GELU. f32x4 per thread.
// grid = B*N*HID/1024 = 2048 blocks x 256.
// ---------------------------------------------------------------------------
__global__ __launch_bounds__(256) void combine_kernel(
    const float* __restrict__ Op, const float* __restrict__ Zp,
    float* __restrict__ out, int S)
{
    int g = blockIdx.x * 256 + threadIdx.x;       // float4 index
    int c4 = g & 63;
    int n  = (g >> 6) & (Nc - 1);
    int b  = g >> 18;                             // 64 * 4096 = 2^18
    int h  = c4 >> 4;

    float z = 0.f;
    float4 v = {0.f, 0.f, 0.f, 0.f};
    for (int s = 0; s < S; s++) {
        z += Zp[(((size_t)s * Bc + b) * Hc + h) * Nc + n];
        float4 p = *(const float4*)&Op[(((size_t)s * Bc + b) * Nc + n) * HIDc + c4 * 4];
        v.x += p.x; v.y += p.y; v.z += p.z; v.w += p.w;
    }
    float iz = 1.0f / z;
    float4 o;
    float u;
    u = v.x * iz; o.x = 0.5f * u * (1.0f + erff(u * 0.7071067811865476f));
    u = v.y * iz; o.y = 0.5f * u * (1.0f + erff(u * 0.7071067811865476f));
    u = v.z * iz; o.z = 0.5f * u * (1.0f + erff(u * 0.7071067811865476f));
    u = v.w * iz; o.w = 0.5f * u * (1.0f + erff(u * 0.7071067811865476f));
    *(float4*)&out[(((size_t)b * Nc + n) * HIDc) + c4 * 4] = o;
}

// ---------------------------------------------------------------------------
extern "C" void kernel_launch(void* const* d_in, const int* in_sizes, int n_in,
                              void* d_out, int out_size, void* d_ws, size_t ws_size,
                              hipStream_t stream) {
    const float* m_dist = (const float*)d_in[0];
    const float* x      = (const float*)d_in[1];
    const float* r      = (const float*)d_in[2];
    const float* weight = (const float*)d_in[3];
    float* out = (float*)d_out;

    char* ws = (char*)d_ws;
    const size_t MB = 1024 * 1024;
    unsigned short* vt = (unsigned short*)ws;            // 4 MiB bf16 VT
    float* thr = (float*)(ws + 4 * MB);                  // 32 KiB
    float* mn  = (float*)(ws + 4 * MB + 32 * 1024);      // 32 KiB
    float* Zp  = (float*)(ws + 4 * MB + 64 * 1024);      // up to 512 KiB
    float* Op  = (float*)(ws + 5 * MB);                  // S * 8 MiB

    const size_t OpSz = (size_t)Bc * Nc * HIDc * 4;      // 8 MiB
    // split factor: prefer 4, else 2, else 1 (needs 5MB + S*OpSz + 256KB)
    int S = 4;
    if (ws_size < 6 * MB + 4 * OpSz) S = 2;
    if (ws_size < 6 * MB + 2 * OpSz) S = 1;
    int jlen = Nc / S;

    // W hi/lo fragment buffers after Op (128 KiB each)
    char* pb = ws + 5 * MB + (size_t)S * OpSz;
    unsigned short* wh = (unsigned short*)pb;
    unsigned short* wl = (unsigned short*)(pb + 128 * 1024);

    front_kernel<<<128 + Bc * Nc, 256, 0, stream>>>(m_dist, weight, wh, wl, thr, mn);
    value_kernel<<<512, 256, 0, stream>>>(x, wh, wl, vt);
    attn_kernel<<<S * Bc * (Nc / NT), 1024, 0, stream>>>(m_dist, r, vt, thr, mn, Op, Zp, jlen);
    combine_kernel<<<(Bc * Nc * HIDc) / 1024, 256, 0, stream>>>(Op, Zp, out, S);
}